// Round 14
// baseline (199.110 us; speedup 1.0000x reference)
//
#include <hip/hip_runtime.h>
#include <hip/hip_bf16.h>
#include <hip/hip_cooperative_groups.h>

#define Bv 32
#define Dv 512
#define Kv 64
#define Nv 1024
#define EPSv 1e-12f

typedef __attribute__((ext_vector_type(8))) short bf16x8;
typedef __attribute__((ext_vector_type(4))) float f32x4;

// fp32 -> bf16 (RNE), bit-level
__device__ __forceinline__ unsigned short f2b(float f) {
  union { float f; unsigned u; } v; v.f = f;
  unsigned r = v.u + 0x7fffu + ((v.u >> 16) & 1u);
  return (unsigned short)(r >> 16);
}
__device__ __forceinline__ unsigned pack2(float a, float b) {
  return (unsigned)f2b(a) | ((unsigned)f2b(b) << 16);
}
// HW packed cvt, RNE — same rounding as f2b/pack2. lo = a, hi = b.
__device__ __forceinline__ unsigned cvtpk(float a, float b) {
  unsigned r;
  asm("v_cvt_pk_bf16_f32 %0, %1, %2" : "=v"(r) : "v"(a), "v"(b));
  return r;
}

// global -> LDS direct copy, 16B per lane, no dest VGPRs (deep MLP).
#define GLOAD_LDS16(gsrc, ldst)                                             \
  __builtin_amdgcn_global_load_lds(                                         \
      (const __attribute__((address_space(1))) void*)(gsrc),                \
      (__attribute__((address_space(3))) void*)(ldst), 16, 0, 0)

// ---------------------------------------------------------------------------
// Kernel W: convert conv_w (K x D fp32) -> bf16, AND zero asum+colsq.
// ---------------------------------------------------------------------------
__global__ __launch_bounds__(256) void wconv(const float* __restrict__ w,
                                             unsigned short* __restrict__ wbf,
                                             float* __restrict__ zbuf) {
  int id = blockIdx.x * 256 + threadIdx.x;
  int i = id * 4;
  float4 v = *(const float4*)&w[i];
  uint2 o = make_uint2(pack2(v.x, v.y), pack2(v.z, v.w));
  *(uint2*)&wbf[i] = o;
  if (id < 2 * Bv * Kv) zbuf[id] = 0.f;   // asum (B*K) + colsq (B*K)
}

// ---------------------------------------------------------------------------
// Kernel 1 (fused T+A) — byte-identical to R18 (verified 122.36 total):
// asm depth-8 staging ring, counted vmcnt, tiled assign, co-XCD grid.
// ---------------------------------------------------------------------------
__global__ __launch_bounds__(512) void fused_scores(
    const float* __restrict__ x, const unsigned short* __restrict__ wbf,
    unsigned short* __restrict__ assign, float* __restrict__ asum) {
  __shared__ unsigned short xT[64 * 520];   // [n][d], pitch 520 shorts
  __shared__ float redmax[4][64];
  __shared__ float redsum[4][64];

  const int t = threadIdx.x;   // 0..511
  const int flat = blockIdx.x;            // 0..511
  const int i0 = flat >> 3;               // 0..63
  const int b = (flat & 7) + 8 * (i0 & 3);
  const int nt = i0 >> 2;                 // 0..15
  const int n0 = nt * 64;

  // ---------------- staging (asm depth-8 ring) ----------------
  {
    const int lo = t & 15;
    const int hi = t >> 4;
    const int s = (lo >> 1) & 3;
    const float* xb = x + (size_t)b * Dv * Nv + n0 + lo * 4;
    float4 xr0[4], xr1[4];

#define FS_ISSUE(slot, r)                                                     \
  {                                                                           \
    const float* _s = xb + (size_t)((hi + 32 * (r)) * 2) * Nv;                \
    asm volatile("global_load_dwordx4 %0, %1, off"                            \
                 : "=v"(xr0[slot]) : "v"(_s));                                \
    asm volatile("global_load_dwordx4 %0, %1, off"                            \
                 : "=v"(xr1[slot]) : "v"(_s + Nv));                           \
  }

    FS_ISSUE(0, 0) FS_ISSUE(1, 1) FS_ISSUE(2, 2) FS_ISSUE(3, 3)
    __builtin_amdgcn_sched_barrier(0);

#pragma unroll
    for (int r = 0; r < 8; r++) {
      const int nout = (r < 5) ? 6 : (14 - 2 * r);   // 6,6,6,6,6,4,2,0
      asm volatile("s_waitcnt vmcnt(%0)" :: "i"(nout));
      __builtin_amdgcn_sched_barrier(0);
      float4 v0 = xr0[r & 3];
      float4 v1 = xr1[r & 3];
      int d = (hi + 32 * r) * 2;
      int n4 = lo * 4;
      unsigned w0 = pack2(v0.x, v1.x);
      unsigned w1 = pack2(v0.y, v1.y);
      unsigned w2 = pack2(v0.z, v1.z);
      unsigned w3 = pack2(v0.w, v1.w);
      unsigned a0 = (s & 1) ? w1 : w0, a1 = (s & 1) ? w2 : w1,
               a2 = (s & 1) ? w3 : w2, a3 = (s & 1) ? w0 : w3;
      unsigned b0 = (s & 2) ? a2 : a0, b1 = (s & 2) ? a3 : a1,
               b2 = (s & 2) ? a0 : a2, b3 = (s & 2) ? a1 : a3;
      *(unsigned*)&xT[(n4 + ((0 + s) & 3)) * 520 + d] = b0;
      *(unsigned*)&xT[(n4 + ((1 + s) & 3)) * 520 + d] = b1;
      *(unsigned*)&xT[(n4 + ((2 + s) & 3)) * 520 + d] = b2;
      *(unsigned*)&xT[(n4 + ((3 + s) & 3)) * 520 + d] = b3;
      if (r < 4) FS_ISSUE(r & 3, r + 4)
      __builtin_amdgcn_sched_barrier(0);
    }
#undef FS_ISSUE
  }
  __syncthreads();

  // ---------------- scores GEMM ----------------
  const int wv = t >> 6;
  const int lane = t & 63;
  const int q = lane >> 4;
  const int m = lane & 15;
  const int k16 = wv & 3;
  const int nsub = wv >> 2;

  f32x4 acc0 = {0.f, 0.f, 0.f, 0.f};
  f32x4 acc1 = {0.f, 0.f, 0.f, 0.f};

  const unsigned short* wp = wbf + (size_t)(k16 * 16 + m) * Dv + q * 8;
  const unsigned short* l0 = &xT[(nsub * 32 + m) * 520 + q * 8];
  const unsigned short* l1 = l0 + 16 * 520;

#pragma unroll
  for (int d0 = 0; d0 < Dv; d0 += 32) {
    bf16x8 af = *(const bf16x8*)(wp + d0);
    bf16x8 bf0 = *(const bf16x8*)(l0 + d0);
    bf16x8 bf1 = *(const bf16x8*)(l1 + d0);
    acc0 = __builtin_amdgcn_mfma_f32_16x16x32_bf16(af, bf0, acc0, 0, 0, 0);
    acc1 = __builtin_amdgcn_mfma_f32_16x16x32_bf16(af, bf1, acc1, 0, 0, 0);
  }

  // ---------------- softmax over k (64) ----------------
  float m0 = fmaxf(fmaxf(acc0[0], acc0[1]), fmaxf(acc0[2], acc0[3]));
  float m1 = fmaxf(fmaxf(acc1[0], acc1[1]), fmaxf(acc1[2], acc1[3]));
  m0 = fmaxf(m0, __shfl_xor(m0, 16)); m0 = fmaxf(m0, __shfl_xor(m0, 32));
  m1 = fmaxf(m1, __shfl_xor(m1, 16)); m1 = fmaxf(m1, __shfl_xor(m1, 32));
  if (q == 0) {
    redmax[k16][nsub * 32 + m] = m0;
    redmax[k16][nsub * 32 + 16 + m] = m1;
  }
  __syncthreads();
  const int c0 = nsub * 32 + m, c1 = c0 + 16;
  float mc0 = fmaxf(fmaxf(redmax[0][c0], redmax[1][c0]), fmaxf(redmax[2][c0], redmax[3][c0]));
  float mc1 = fmaxf(fmaxf(redmax[0][c1], redmax[1][c1]), fmaxf(redmax[2][c1], redmax[3][c1]));

  float e0[4], e1[4];
  float s0 = 0.f, s1 = 0.f;
#pragma unroll
  for (int r = 0; r < 4; r++) {
    e0[r] = __expf(acc0[r] - mc0); s0 += e0[r];
    e1[r] = __expf(acc1[r] - mc1); s1 += e1[r];
  }
  s0 += __shfl_xor(s0, 16); s0 += __shfl_xor(s0, 32);
  s1 += __shfl_xor(s1, 16); s1 += __shfl_xor(s1, 32);
  if (q == 0) {
    redsum[k16][c0] = s0;
    redsum[k16][c1] = s1;
  }
  __syncthreads();
  float sc0 = 1.0f / (redsum[0][c0] + redsum[1][c0] + redsum[2][c0] + redsum[3][c0]);
  float sc1 = 1.0f / (redsum[0][c1] + redsum[1][c1] + redsum[2][c1] + redsum[3][c1]);

  unsigned short* at_ = assign + ((size_t)b * 16 + nt) * (Kv * 64)
                        + (size_t)(k16 * 16 + q * 4) * 64 + nsub * 32;
#pragma unroll
  for (int r = 0; r < 4; r++) {
    float v0 = e0[r] * sc0;
    float v1 = e1[r] * sc1;
    at_[r * 64 + m] = f2b(v0);
    at_[r * 64 + 16 + m] = f2b(v1);
    float p = v0 + v1;
    p += __shfl_xor(p, 1); p += __shfl_xor(p, 2);
    p += __shfl_xor(p, 4); p += __shfl_xor(p, 8);
    if (m == 0) atomicAdd(&asum[b * Kv + k16 * 16 + q * 4 + r], p);
  }
}

// ---------------------------------------------------------------------------
// Kernel 2 (R19): R17's verified LDS-staged GEMM + FUSED final scaling via
// cooperative grid sync. Epilogue keeps the corrected vals in registers,
// atomicAdds colsq, grid.sync() (device-scope fence -> all colsq complete),
// computes scs/bsh in-block (ex-scale_kernel logic), scales the register
// vals and writes out DIRECTLY. Eliminates the vlad buffer (8 MB traffic),
// the scale dispatch, and one launch gap.
// Co-residency (cooperative requirement): LDS 65.8KB -> 2 blk/CU;
// launch_bounds(256,2) -> <=128 VGPR; grid 512 = 2 x 256 CUs exactly.
// ---------------------------------------------------------------------------
__global__ __launch_bounds__(256, 2) void vlad_stage(
    const float* __restrict__ x, const unsigned short* __restrict__ assign,
    const float* __restrict__ centers, const float* __restrict__ asum,
    float* __restrict__ out, float* __restrict__ colsq) {
  __shared__ float xsf[2][2][2048];            // [buf][tile][32d x 64n] 8KB
  __shared__ unsigned short as_[2][2][4096];   // [buf][tile][64k x 64n] 8KB
  __shared__ float scs[64];
  __shared__ float bshs;

  const int t = threadIdx.x;
  const int flat = blockIdx.x;            // 0..511
  const int i0 = flat >> 3;               // 0..63
  const int b = (flat & 7) + 8 * (i0 & 3);
  const int dg = i0 >> 2;                 // 0..15 -> d base dg*32

  const int w = t >> 6;                   // wave 0..3
  const int dh = w & 1;                   // 16-d half
  const int kh = w >> 1;                  // 32-k half
  const int lane = t & 63;
  const int q = lane >> 4;
  const int m = lane & 15;

  const int rs = lane >> 3;               // row-sub 0..7
  const int csw_a = (lane & 7) ^ (rs & 7);
  const int rx = lane >> 4;               // 0..3

  const float* xdg = x + ((size_t)b * Dv + dg * 32) * Nv;
  const unsigned short* abase = assign + (size_t)b * 16 * (Kv * 64);

  // 8 gload_lds per thread per STAGE (4 x-slab + 4 a-slab)
#define STAGE(buf, rr)                                                        \
  {                                                                           \
    _Pragma("unroll")                                                         \
    for (int s = 0; s < 2; s++) {                                             \
      int tile = (rr) * 2 + s;                                                \
      _Pragma("unroll")                                                       \
      for (int i = 0; i < 2; i++) {                                           \
        int dl = w * 8 + i * 4 + rx;      /* local d row 0..31 */             \
        const float* _xs = xdg + (size_t)dl * Nv + tile * 64                  \
                           + (((lane & 15) ^ (dl & 7)) * 4);                  \
        GLOAD_LDS16(_xs, &xsf[buf][s][(w * 8 + i * 4) * 64]);                 \
      }                                                                       \
      const unsigned short* _a1 = abase + (size_t)tile * (Kv * 64)            \
                                  + (w * 16 + rs) * 64 + csw_a * 8;           \
      GLOAD_LDS16(_a1, &as_[buf][s][w * 1024]);                               \
      GLOAD_LDS16(_a1 + 512, &as_[buf][s][w * 1024 + 512]);                   \
    }                                                                         \
  }

  f32x4 acc0 = {0.f,0.f,0.f,0.f}, acc1 = {0.f,0.f,0.f,0.f};

  STAGE(0, 0)
  STAGE(1, 1)
  asm volatile("s_waitcnt vmcnt(8)");     // pair0's 8 done (8 younger remain)
  __builtin_amdgcn_sched_barrier(0);
  __builtin_amdgcn_s_barrier();
  __builtin_amdgcn_sched_barrier(0);

  const int row = dh * 16 + m;            // x LDS row
  const int mk7 = m & 7;
#pragma unroll
  for (int rr = 0; rr < 8; rr++) {
    const int buf = rr & 1;
#pragma unroll
    for (int s = 0; s < 2; s++) {
#pragma unroll
      for (int nc = 0; nc < 2; nc++) {
        const int c0 = nc * 8 + q * 2;
        float4 f0 = *(const float4*)&xsf[buf][s][row * 64 + ((c0 ^ mk7)) * 4];
        float4 f1 = *(const float4*)&xsf[buf][s][row * 64 + (((c0 + 1) ^ mk7)) * 4];
        bf16x8 xv;
        unsigned* xu = (unsigned*)&xv;
        xu[0] = cvtpk(f0.x, f0.y);
        xu[1] = cvtpk(f0.z, f0.w);
        xu[2] = cvtpk(f1.x, f1.y);
        xu[3] = cvtpk(f1.z, f1.w);
        const int cidx = ((nc * 4 + q) ^ mk7) * 8;
        bf16x8 a0 = *(const bf16x8*)&as_[buf][s][(kh * 32 + m) * 64 + cidx];
        bf16x8 a1 = *(const bf16x8*)&as_[buf][s][(kh * 32 + 16 + m) * 64 + cidx];
        acc0 = __builtin_amdgcn_mfma_f32_16x16x32_bf16(xv, a0, acc0, 0, 0, 0);
        acc1 = __builtin_amdgcn_mfma_f32_16x16x32_bf16(xv, a1, acc1, 0, 0, 0);
      }
    }
    if (rr < 7) {
      __builtin_amdgcn_sched_barrier(0);
      __builtin_amdgcn_s_barrier();       // all waves done reading buf
      __builtin_amdgcn_sched_barrier(0);
      if (rr < 6) {
        STAGE(buf, rr + 2)                // refill buf with pair rr+2
        asm volatile("s_waitcnt vmcnt(8)");  // older 8 (pair rr+1) done
      } else {
        asm volatile("s_waitcnt vmcnt(0)");  // last pair (7) done
      }
      __builtin_amdgcn_sched_barrier(0);
      __builtin_amdgcn_s_barrier();       // pair rr+1 visible to all
      __builtin_amdgcn_sched_barrier(0);
    }
  }
#undef STAGE

  // epilogue A: centers correction in registers + colsq atomics
  const int k0 = kh * 32 + m;
  const int k1 = k0 + 16;
  const float as0 = asum[b * Kv + k0];
  const float as1 = asum[b * Kv + k1];
  float v0a[4], v1a[4];
  float ss0 = 0.f, ss1 = 0.f;
#pragma unroll
  for (int r = 0; r < 4; r++) {
    int d = dg * 32 + dh * 16 + q * 4 + r;
    v0a[r] = acc0[r] - centers[d * Kv + k0] * as0;
    v1a[r] = acc1[r] - centers[d * Kv + k1] * as1;
    ss0 = fmaf(v0a[r], v0a[r], ss0);
    ss1 = fmaf(v1a[r], v1a[r], ss1);
  }
  ss0 += __shfl_xor(ss0, 16); ss0 += __shfl_xor(ss0, 32);
  ss1 += __shfl_xor(ss1, 16); ss1 += __shfl_xor(ss1, 32);
  if (q == 0) {
    atomicAdd(&colsq[b * Kv + k0], ss0);
    atomicAdd(&colsq[b * Kv + k1], ss1);
  }

  // ---- grid-wide sync: all colsq complete (device-scope fence) ----
  cooperative_groups::this_grid().sync();

  // epilogue B (ex-scale_kernel): scs/bsh in-block, scale regs, write out
  if (t < 64) {
    float tot = colsq[b * Kv + t];
    float sc = 1.0f / fmaxf(sqrtf(tot), EPSv);
    scs[t] = sc;
    float contrib = tot * sc * sc;
#pragma unroll
    for (int off = 32; off > 0; off >>= 1) contrib += __shfl_down(contrib, off);
    if (t == 0) bshs = 1.0f / fmaxf(sqrtf(contrib), EPSv);
  }
  __syncthreads();
  const float bsh = bshs;
  const float c0s = scs[k0] * bsh;
  const float c1s = scs[k1] * bsh;
#pragma unroll
  for (int r = 0; r < 4; r++) {
    int d = dg * 32 + dh * 16 + q * 4 + r;
    out[((size_t)b * Dv + d) * Kv + k0] = v0a[r] * c0s;
    out[((size_t)b * Dv + d) * Kv + k1] = v1a[r] * c1s;
  }
}

extern "C" void kernel_launch(void* const* d_in, const int* in_sizes, int n_in,
                              void* d_out, int out_size, void* d_ws, size_t ws_size,
                              hipStream_t stream) {
  const float* x = (const float*)d_in[0];        // [B, D, N]
  const float* w = (const float*)d_in[1];        // [K, D]
  const float* centers = (const float*)d_in[2];  // [D, K]
  float* out = (float*)d_out;                    // [B, D*K]

  char* ws = (char*)d_ws;
  unsigned short* assign = (unsigned short*)ws;               // tiled, 4 MB
  unsigned short* wbf = (unsigned short*)(ws + 4194304);      // [K][D] bf16, 64 KB
  float* asum = (float*)(ws + 4259840);                       // B*K
  float* colsq = asum + Bv * Kv;                              // B*K

  wconv<<<32, 256, 0, stream>>>(w, wbf, asum);   // also zeros asum+colsq
  fused_scores<<<512, 512, 0, stream>>>(x, wbf, assign, asum);

  void* vsargs[] = {(void*)&x, (void*)&assign, (void*)&centers,
                    (void*)&asum, (void*)&out, (void*)&colsq};
  hipLaunchCooperativeKernel(reinterpret_cast<void*>(vlad_stage),
                             dim3(512), dim3(256), vsargs, 0, stream);
}